// Round 14
// baseline (177.787 us; speedup 1.0000x reference)
//
#include <hip/hip_runtime.h>

#define NN 4096
#define F_IN 1024
#define NHEAD 8
#define HID 64
#define NCLS 40
#define LOG2E 1.44269504f

typedef float f32x4 __attribute__((ext_vector_type(4)));
typedef float f32x2 __attribute__((ext_vector_type(2)));
typedef short s16x8 __attribute__((ext_vector_type(8)));

// XOR-swizzled halfword index within a [R][64]-hw (128B-row) LDS tile.
#define SWZ(r,c) (((r)*64) + ((c) ^ (((r)&7)<<3)))

__device__ __forceinline__ unsigned short f2bf(float f){  // RNE float->bf16
  unsigned u = __float_as_uint(f);
  return (unsigned short)((u + 0x7fffu + ((u >> 16) & 1u)) >> 16);
}
__device__ __forceinline__ float bf2f(unsigned short u){
  return __uint_as_float((unsigned)u << 16);
}
__device__ __forceinline__ unsigned cvtpk(float lo, float hi){  // packed bf16 pair
  unsigned r; asm("v_cvt_pk_bf16_f32 %0, %1, %2" : "=v"(r) : "v"(lo), "v"(hi)); return r;
}
__device__ __forceinline__ f32x2 pkmul(f32x2 a, f32x2 b){  // packed fp32 dual mul
  f32x2 r; asm("v_pk_mul_f32 %0, %1, %2" : "=v"(r) : "v"(a), "v"(b)); return r;
}

// ---------------- pack adjacency -> word-transposed bitmask ----------------
__global__ __launch_bounds__(256) void pack_adj_k(const int* __restrict__ adj, unsigned* __restrict__ bmT){
  int gid = blockIdx.x*256 + threadIdx.x;
  int lane = threadIdx.x & 63;
  unsigned long long m = __ballot(adj[gid] > 0);
  int w = gid >> 5, i = w >> 7, jw = w & 127;
  if (lane == 0)       bmT[(size_t)jw*NN + i] = (unsigned)m;
  else if (lane == 32) bmT[(size_t)jw*NN + i] = (unsigned)(m >> 32);
}

// ---------------- WbT[h][o][k] = bf16(W[h][k][o]) ----------------
__global__ __launch_bounds__(256) void cast_W_k(const float* __restrict__ W, unsigned short* __restrict__ WbT){
  __shared__ float T[64][65];
  const int h = blockIdx.y, k0 = blockIdx.x*64, t = threadIdx.x;
  for (int idx = t; idx < 1024; idx += 256){
    int k = idx >> 4, c4 = idx & 15;
    *(float4*)&T[k][c4*4] = *(const float4*)&W[((size_t)h*F_IN + k0 + k)*HID + c4*4];
  }
  __syncthreads();
  for (int idx = t; idx < 512; idx += 256){
    int o = idx >> 3, ch = idx & 7;
    s16x8 v;
    #pragma unroll
    for (int e = 0; e < 8; ++e) v[e] = (short)f2bf(T[ch*8 + e][o]);
    *(s16x8*)&WbT[((size_t)h*HID + o)*F_IN + k0 + ch*8] = v;
  }
}

// ---------------- WoT[c][k] = bf16(W_out[k][c]), rows 40..47 zero ----------------
__global__ __launch_bounds__(256) void cast_Wo_k(const float* __restrict__ Wout, unsigned short* __restrict__ WoT){
  int idx = blockIdx.x*256 + threadIdx.x;   // 48*512
  int cc = idx >> 9, k = idx & 511;
  WoT[idx] = (cc < NCLS) ? f2bf(Wout[(size_t)k*NCLS + cc]) : (unsigned short)0;
}

// ---------------- gemm1: WhT[h][o][n] bf16 = (x@W)^T ; srcv/dstv/bdv fused epilogue ----------------
__global__ __launch_bounds__(256) void gemm1_k(const float* __restrict__ x,
    const unsigned short* __restrict__ WbT, unsigned short* __restrict__ WhT,
    const float* __restrict__ a_src, const float* __restrict__ a_dst,
    float* __restrict__ srcv, float* __restrict__ dstv, float2* __restrict__ bdv){
  __shared__ unsigned short xS[64*64];
  __shared__ unsigned short wS[64*64];
  const int t = threadIdx.x, l = t & 63, wv = t >> 6, g = l >> 4, c = l & 15;
  const int h = blockIdx.y, n0 = blockIdx.x * 64;
  f32x4 acc[4] = {};
  for (int k0 = 0; k0 < F_IN; k0 += 64){
    __syncthreads();
    #pragma unroll
    for (int p = 0; p < 4; ++p){
      int idx = t + p*256, row = idx >> 4, c4 = idx & 15;
      float4 v = *(const float4*)&x[(size_t)(n0+row)*F_IN + k0 + c4*4];
      *(uint2*)&xS[SWZ(row, c4*4)] = make_uint2(cvtpk(v.x, v.y), cvtpk(v.z, v.w));
    }
    #pragma unroll
    for (int p = 0; p < 2; ++p){
      int idx = t + p*256, o = idx >> 3, ch = idx & 7;
      *(s16x8*)&wS[SWZ(o, ch*8)] = *(const s16x8*)&WbT[(size_t)(h*HID + o)*F_IN + k0 + ch*8];
    }
    __syncthreads();
    #pragma unroll
    for (int ks = 0; ks < 2; ++ks){
      s16x8 av = *(const s16x8*)&xS[SWZ(wv*16 + c, ks*32 + g*8)];
      #pragma unroll
      for (int ct = 0; ct < 4; ++ct){
        s16x8 bv = *(const s16x8*)&wS[SWZ(ct*16 + c, ks*32 + g*8)];
        acc[ct] = __builtin_amdgcn_mfma_f32_16x16x32_bf16(av, bv, acc[ct], 0, 0, 0);
      }
    }
  }
  float asv[4], adv[4];
  #pragma unroll
  for (int ct = 0; ct < 4; ++ct){ asv[ct] = a_src[h*HID + ct*16 + c]; adv[ct] = a_dst[h*HID + ct*16 + c]; }
  #pragma unroll
  for (int r = 0; r < 4; ++r){
    float ps = acc[0][r]*asv[0] + acc[1][r]*asv[1] + acc[2][r]*asv[2] + acc[3][r]*asv[3];
    float pd = acc[0][r]*adv[0] + acc[1][r]*adv[1] + acc[2][r]*adv[2] + acc[3][r]*adv[3];
    #pragma unroll
    for (int off = 1; off < 16; off <<= 1){ ps += __shfl_xor(ps, off); pd += __shfl_xor(pd, off); }
    if (c == 0){
      int n = n0 + wv*16 + g*4 + r;
      srcv[h*NN + n] = ps; dstv[h*NN + n] = pd;
      bdv[h*NN + n] = make_float2(exp2f(pd*LOG2E), exp2f(0.2f*pd*LOG2E));
    }
  }
  __syncthreads();
  #pragma unroll
  for (int ct = 0; ct < 4; ++ct)
    *(uint2*)&xS[SWZ(ct*16 + c, wv*16 + g*4)] = make_uint2(cvtpk(acc[ct][0], acc[ct][1]), cvtpk(acc[ct][2], acc[ct][3]));
  __syncthreads();
  #pragma unroll
  for (int p = 0; p < 2; ++p){
    int idx = t + p*256, o = idx >> 3, ch = idx & 7;
    *(s16x8*)&WhT[(size_t)(h*HID + o)*NN + n0 + ch*8] = *(const s16x8*)&xS[SWZ(o, ch*8)];
  }
}

// ---------------- per-4096-segment max reduce ----------------
__global__ __launch_bounds__(256) void maxred_k(const float* __restrict__ in, float* __restrict__ out){
  __shared__ float red[4];
  const float* p = in + (size_t)blockIdx.x*NN;
  float m = -3.0e38f;
  for (int i = threadIdx.x; i < NN; i += 256) m = fmaxf(m, p[i]);
  #pragma unroll
  for (int off = 32; off; off >>= 1) m = fmaxf(m, __shfl_xor(m, off));
  if ((threadIdx.x & 63) == 0) red[threadIdx.x >> 6] = m;
  __syncthreads();
  if (threadIdx.x == 0) out[blockIdx.x] = fmaxf(fmaxf(red[0], red[1]), fmaxf(red[2], red[3]));
}

// ---------------- MFMA masked-softmax aggregate v5: 64-row shared-tile, no merge ----------------
// Block: 64 rows; 4 waves each own 16 rows (wave wv -> rows i0+wv*16..+16), ALL consume the
// same j-tile from a shared double-buffered vS (18 KB LDS -> 8 blocks/CU).
// Per iteration: loadRegs(next) -> computeBuf(cur) -> writeLDS(cur^1) -> one barrier.
// p_ij = bit * med3(A_i*B_j, C_i*D_j, 1); (B,D) from bdv. Row sums via ones-MFMA.
// MODE 0 (L1): blockIdx.y = h*4+ck; bf16 partials [ck][row][512], fp32 den[(ck*8+h)*NN+row].
// MODE 1 (L2): blockIdx.y = ck (16 chunks); fp32 partials [ck][row][64], den in col 48.
template<int NCT, int NJT, int MODE>
__global__ __launch_bounds__(256, 8) void agg_mfma_k(
    const unsigned* __restrict__ bmT, const unsigned short* __restrict__ VT,
    const float* __restrict__ srcv, const float2* __restrict__ bdv,
    const float* __restrict__ maxp, void* __restrict__ partOut, float* __restrict__ denOut)
{
  __shared__ unsigned short vS[2][NCT*16*64];
  __shared__ float2 dS[2][64];
  __shared__ unsigned bitS[2][2][64];
  const int t = threadIdx.x, l = t & 63, wv = t >> 6, g = l >> 4, c = l & 15;
  const int h  = (MODE == 0) ? (blockIdx.y >> 2) : 0;
  const int ck = (MODE == 0) ? (blockIdx.y & 3)  : blockIdx.y;
  const int jt0 = ck * NJT;
  const int i0 = blockIdx.x * 64;
  const int lr = wv*16 + c;                 // local row (0..63)
  const float sr = srcv[h*NN + i0 + lr];
  const float mx = maxp[MODE == 0 ? h : 0];
  const float tm = sr + mx;
  const float mi2 = fmaxf(tm, 0.2f*tm) * LOG2E;
  f32x2 ac2;
  ac2[0] = exp2f(fmaf(sr, LOG2E, -mi2));        // A_i
  ac2[1] = exp2f(fmaf(0.2f*sr, LOG2E, -mi2));   // C_i
  const unsigned short* vb = VT + (MODE == 0 ? (size_t)h*HID*NN : (size_t)0);
  const float2* bp = bdv + (MODE == 0 ? (size_t)h*NN : (size_t)0);

  f32x4 acc[NCT] = {};
  f32x4 accs = {};
  s16x8 ones;
  #pragma unroll
  for (int e = 0; e < 8; ++e) ones[e] = (short)0x3F80;

  s16x8 vreg[2]; float2 dreg = make_float2(0.f, 0.f); unsigned breg = 0;
  auto loadRegs = [&](int jt){
    #pragma unroll
    for (int p = 0; p < 2; ++p){
      int u = t + p*256;
      if (u < NCT*128){
        int o = u >> 3, chk = u & 7;
        vreg[p] = *(const s16x8*)&vb[(size_t)o*NN + jt*64 + chk*8];
      }
    }
    if (t < 64) { f32x2 bd = *(const f32x2*)&bp[jt*64 + t]; dreg = make_float2(bd[0], bd[1]); }
    else if (t < 192){ int u = t - 64; breg = bmT[(size_t)(jt*2 + (u>>6))*NN + i0 + (u & 63)]; }
  };
  auto writeLDS = [&](int b){
    #pragma unroll
    for (int p = 0; p < 2; ++p){
      int u = t + p*256;
      if (u < NCT*128){
        int o = u >> 3, chk = u & 7;
        *(s16x8*)&vS[b][SWZ(o, chk*8)] = vreg[p];
      }
    }
    if (t < 64) dS[b][t] = dreg;
    else if (t < 192){ int u = t - 64; bitS[b][u>>6][u&63] = breg; }
  };
  auto computeBuf = [&](int b){
    #pragma unroll
    for (int ks = 0; ks < 2; ++ks){
      unsigned wb = (bitS[b][ks][lr] >> (g*8)) & 0xffu;
      const f32x2* dr = (const f32x2*)&dS[b][ks*32 + g*8];
      float q[8];
      #pragma unroll
      for (int e = 0; e < 8; ++e){
        f32x2 pr = pkmul(ac2, dr[e]);
        float m3 = __builtin_amdgcn_fmed3f(pr[0], pr[1], 1.0f);
        q[e] = (wb & (1u << e)) ? m3 : 0.f;
      }
      s16x8 afr;
      ((unsigned*)&afr)[0] = cvtpk(q[0], q[1]);
      ((unsigned*)&afr)[1] = cvtpk(q[2], q[3]);
      ((unsigned*)&afr)[2] = cvtpk(q[4], q[5]);
      ((unsigned*)&afr)[3] = cvtpk(q[6], q[7]);
      #pragma unroll
      for (int ct = 0; ct < NCT; ++ct){
        s16x8 bv = *(const s16x8*)&vS[b][SWZ(ct*16 + c, ks*32 + g*8)];
        acc[ct] = __builtin_amdgcn_mfma_f32_16x16x32_bf16(afr, bv, acc[ct], 0, 0, 0);
      }
      accs = __builtin_amdgcn_mfma_f32_16x16x32_bf16(afr, ones, accs, 0, 0, 0);
    }
  };

  // prologue
  loadRegs(jt0);
  writeLDS(0);
  __syncthreads();
  int cur = 0;
  for (int jj = 0; jj < NJT; ++jj){
    const bool more = (jj + 1 < NJT);
    if (more) loadRegs(jt0 + jj + 1);   // issue next-tile loads early
    computeBuf(cur);
    if (more) writeLDS(cur ^ 1);        // write-late into other buffer
    __syncthreads();                    // single barrier per iteration
    cur ^= 1;
  }

  // epilogue: wave wv owns complete rows i0 + wv*16 + g*4 + r (no merge needed)
  if (MODE == 0){
    unsigned short* ob = (unsigned short*)partOut + (size_t)ck * NN * (NHEAD*HID);
    #pragma unroll
    for (int r = 0; r < 4; ++r){
      int row = i0 + wv*16 + g*4 + r;
      #pragma unroll
      for (int ct = 0; ct < NCT; ++ct)
        ob[(size_t)row*(NHEAD*HID) + h*HID + ct*16 + c] = f2bf(acc[ct][r]);
      if (c == 0) denOut[(size_t)(ck*NHEAD + h)*NN + row] = accs[r];
    }
  } else {
    float* ob = (float*)partOut + (size_t)ck * NN * 64;
    #pragma unroll
    for (int r = 0; r < 4; ++r){
      int row = i0 + wv*16 + g*4 + r;
      #pragma unroll
      for (int ct = 0; ct < NCT; ++ct)
        ob[(size_t)row*64 + ct*16 + c] = acc[ct][r];
      if (c == 0) ob[(size_t)row*64 + 48] = accs[r];
    }
  }
}

// ---------------- layer-1 merge: 4 bf16 chunks -> normalize -> elu -> bf16 hbuf ----------------
__global__ __launch_bounds__(256) void merge1_k(const unsigned short* __restrict__ part,
                                                const float* __restrict__ den,
                                                unsigned short* __restrict__ hb){
  int idx = blockIdx.x*256 + threadIdx.x;   // NN*128 threads
  int row = idx >> 7, q = idx & 127;
  int h = q >> 4;
  float v[4] = {0.f, 0.f, 0.f, 0.f};
  float dn = 0.f;
  #pragma unroll
  for (int ck = 0; ck < 4; ++ck){
    const unsigned short* pb = part + ((size_t)ck*NN + row)*(NHEAD*HID) + q*4;
    ushort4 u = *(const ushort4*)pb;
    v[0] += bf2f(u.x); v[1] += bf2f(u.y); v[2] += bf2f(u.z); v[3] += bf2f(u.w);
    dn += den[(size_t)(ck*NHEAD + h)*NN + row];
  }
  float inv = 1.f / fmaxf(dn, 1e-30f);
  #pragma unroll
  for (int e = 0; e < 4; ++e){
    float x = v[e]*inv;
    v[e] = x > 0.f ? x : __expf(x) - 1.f;
  }
  *(uint2*)&hb[(size_t)row*(NHEAD*HID) + q*4] = make_uint2(cvtpk(v[0], v[1]), cvtpk(v[2], v[3]));
}

// ---------------- gemm2: WhT2[c][n] bf16 = (h_bf16 @ W_out)^T ; s2/d2/bd2 fused ----------------
__global__ __launch_bounds__(256) void gemm2_k(const unsigned short* __restrict__ hb,
    const unsigned short* __restrict__ WoT, const float* __restrict__ aos, const float* __restrict__ aod,
    unsigned short* __restrict__ WhT2, float* __restrict__ s2, float* __restrict__ d2,
    float2* __restrict__ bd2){
  __shared__ unsigned short aS[64*64];
  __shared__ unsigned short bS[48*64];
  const int t = threadIdx.x, l = t & 63, wv = t >> 6, g = l >> 4, c = l & 15;
  const int n0 = blockIdx.x * 64;
  f32x4 acc[3] = {};
  for (int k0 = 0; k0 < NHEAD*HID; k0 += 64){
    __syncthreads();
    #pragma unroll
    for (int p = 0; p < 2; ++p){
      int u = t + p*256, o = u >> 3, ch = u & 7;
      *(s16x8*)&aS[SWZ(o, ch*8)] = *(const s16x8*)&hb[(size_t)(n0+o)*(NHEAD*HID) + k0 + ch*8];
    }
    for (int u = t; u < 384; u += 256){
      int o = u >> 3, ch = u & 7;
      *(s16x8*)&bS[SWZ(o, ch*8)] = *(const s16x8*)&WoT[(size_t)o*(NHEAD*HID) + k0 + ch*8];
    }
    __syncthreads();
    #pragma unroll
    for (int ks = 0; ks < 2; ++ks){
      s16x8 av = *(const s16x8*)&aS[SWZ(wv*16 + c, ks*32 + g*8)];
      #pragma unroll
      for (int ct = 0; ct < 3; ++ct){
        s16x8 bv = *(const s16x8*)&bS[SWZ(ct*16 + c, ks*32 + g*8)];
        acc[ct] = __builtin_amdgcn_mfma_f32_16x16x32_bf16(av, bv, acc[ct], 0, 0, 0);
      }
    }
  }
  float asv[3], adv[3];
  #pragma unroll
  for (int ct = 0; ct < 3; ++ct){
    int col = ct*16 + c;
    asv[ct] = (col < NCLS) ? aos[col] : 0.f;
    adv[ct] = (col < NCLS) ? aod[col] : 0.f;
  }
  #pragma unroll
  for (int r = 0; r < 4; ++r){
    float ps = acc[0][r]*asv[0] + acc[1][r]*asv[1] + acc[2][r]*asv[2];
    float pd = acc[0][r]*adv[0] + acc[1][r]*adv[1] + acc[2][r]*adv[2];
    #pragma unroll
    for (int off = 1; off < 16; off <<= 1){ ps += __shfl_xor(ps, off); pd += __shfl_xor(pd, off); }
    if (c == 0){
      int n = n0 + wv*16 + g*4 + r;
      s2[n] = ps; d2[n] = pd;
      bd2[n] = make_float2(exp2f(pd*LOG2E), exp2f(0.2f*pd*LOG2E));
    }
  }
  __syncthreads();
  #pragma unroll
  for (int ct = 0; ct < 3; ++ct)
    *(uint2*)&bS[SWZ(ct*16 + c, wv*16 + g*4)] = make_uint2(cvtpk(acc[ct][0], acc[ct][1]), cvtpk(acc[ct][2], acc[ct][3]));
  __syncthreads();
  for (int u = t; u < 384; u += 256){
    int o = u >> 3, ch = u & 7;
    *(s16x8*)&WhT2[(size_t)o*NN + n0 + ch*8] = *(const s16x8*)&bS[SWZ(o, ch*8)];
  }
}

// ---------------- merge 16 chunks + elu + row log_softmax ----------------
__global__ __launch_bounds__(256) void final_k(const float* __restrict__ part, float* __restrict__ out){
  const int wid = (blockIdx.x*256 + threadIdx.x) >> 6;
  const int c = threadIdx.x & 63;
  float acc = 0.f, rs = 0.f;
  #pragma unroll
  for (int ch = 0; ch < 16; ++ch){
    const float* pb = part + ((size_t)ch*NN + wid)*64;
    if (c < 48) acc += pb[c];
    rs += pb[48];
  }
  float v = acc / fmaxf(rs, 1e-30f);
  float e = v > 0.f ? v : __expf(v) - 1.f;
  float ev = (c < NCLS) ? e : -3.0e38f;
  float m = ev;
  #pragma unroll
  for (int off = 32; off; off >>= 1) m = fmaxf(m, __shfl_xor(m, off));
  float ex = (c < NCLS) ? __expf(e - m) : 0.f;
  float s = ex;
  #pragma unroll
  for (int off = 32; off; off >>= 1) s += __shfl_xor(s, off);
  if (c < NCLS) out[(size_t)wid*NCLS + c] = e - m - __logf(s);
}

extern "C" void kernel_launch(void* const* d_in, const int* in_sizes, int n_in,
                              void* d_out, int out_size, void* d_ws, size_t ws_size,
                              hipStream_t stream){
  (void)in_sizes; (void)n_in; (void)out_size; (void)ws_size;
  const float* x     = (const float*)d_in[0];
  const int*   adj   = (const int*)  d_in[1];
  const float* W     = (const float*)d_in[2];
  const float* a_src = (const float*)d_in[3];
  const float* a_dst = (const float*)d_in[4];
  const float* W_out = (const float*)d_in[5];
  const float* aos   = (const float*)d_in[6];
  const float* aod   = (const float*)d_in[7];
  float* out = (float*)d_out;

  char* p = (char*)d_ws;
  unsigned* bmT        = (unsigned*)p;       p += (size_t)NN*128*4;            // 2 MB
  unsigned short* WbT  = (unsigned short*)p; p += (size_t)NHEAD*HID*F_IN*2;    // 1 MB
  unsigned short* WhT  = (unsigned short*)p; p += (size_t)NHEAD*HID*NN*2;      // 4 MB
  unsigned short* hbuf = (unsigned short*)p; p += (size_t)NN*NHEAD*HID*2;      // 4 MB
  unsigned short* WoT  = (unsigned short*)p; p += (size_t)48*NHEAD*HID*2;      // 48 KB
  unsigned short* WhT2 = (unsigned short*)p; p += (size_t)48*NN*2;             // 384 KB
  float* srcv = (float*)p; p += (size_t)NHEAD*NN*4;
  float* dstv = (float*)p; p += (size_t)NHEAD*NN*4;
  float* maxd = (float*)p; p += 256;
  float* s2   = (float*)p; p += (size_t)NN*4;
  float* d2   = (float*)p; p += (size_t)NN*4;
  float* m2   = (float*)p; p += 256;
  float2* bdv1 = (float2*)p; p += (size_t)NHEAD*NN*8;                          // 256 KB
  float2* bdv2 = (float2*)p; p += (size_t)NN*8;                                // 32 KB
  float* den1 = (float*)p; p += (size_t)4*NHEAD*NN*4;                          // 512 KB
  char* partU = p; p += (size_t)16*NN*64*4;                                    // 16 MB (L1 bf16 4-chunk / L2 fp32 16-chunk)

  pack_adj_k<<<(NN*NN)/256, 256, 0, stream>>>(adj, bmT);
  cast_W_k<<<dim3(F_IN/64, NHEAD), 256, 0, stream>>>(W, WbT);
  cast_Wo_k<<<96, 256, 0, stream>>>(W_out, WoT);
  gemm1_k<<<dim3(NN/64, NHEAD), 256, 0, stream>>>(x, WbT, WhT, a_src, a_dst, srcv, dstv, bdv1);
  maxred_k<<<NHEAD, 256, 0, stream>>>(dstv, maxd);
  agg_mfma_k<4, 16, 0><<<dim3(NN/64, NHEAD*4), 256, 0, stream>>>(bmT, WhT, srcv, bdv1, maxd, partU, den1);
  merge1_k<<<(NN*128)/256, 256, 0, stream>>>((const unsigned short*)partU, den1, hbuf);
  gemm2_k<<<NN/64, 256, 0, stream>>>(hbuf, WoT, aos, aod, WhT2, s2, d2, bdv2);
  maxred_k<<<1, 256, 0, stream>>>(d2, m2);
  agg_mfma_k<3, 4, 1><<<dim3(NN/64, 16), 256, 0, stream>>>(bmT, WhT2, s2, bdv2, m2, partU, nullptr);
  final_k<<<NN/4, 256, 0, stream>>>((const float*)partU, out);
}

// Round 15
// 160.443 us; speedup vs baseline: 1.1081x; 1.1081x over previous
//
#include <hip/hip_runtime.h>

#define NN 4096
#define F_IN 1024
#define NHEAD 8
#define HID 64
#define NCLS 40
#define LOG2E 1.44269504f

typedef float f32x4 __attribute__((ext_vector_type(4)));
typedef float f32x2 __attribute__((ext_vector_type(2)));
typedef short s16x8 __attribute__((ext_vector_type(8)));

// XOR-swizzled halfword index within a [R][64]-hw (128B-row) LDS tile.
#define SWZ(r,c) (((r)*64) + ((c) ^ (((r)&7)<<3)))

__device__ __forceinline__ unsigned short f2bf(float f){  // RNE float->bf16
  unsigned u = __float_as_uint(f);
  return (unsigned short)((u + 0x7fffu + ((u >> 16) & 1u)) >> 16);
}
__device__ __forceinline__ float bf2f(unsigned short u){
  return __uint_as_float((unsigned)u << 16);
}
__device__ __forceinline__ unsigned cvtpk(float lo, float hi){  // packed bf16 pair
  unsigned r; asm("v_cvt_pk_bf16_f32 %0, %1, %2" : "=v"(r) : "v"(lo), "v"(hi)); return r;
}
__device__ __forceinline__ f32x2 pkmul(f32x2 a, f32x2 b){  // packed fp32 dual mul
  f32x2 r; asm("v_pk_mul_f32 %0, %1, %2" : "=v"(r) : "v"(a), "v"(b)); return r;
}

// ---------------- pack adjacency -> word-transposed bitmask ----------------
__global__ __launch_bounds__(256) void pack_adj_k(const int* __restrict__ adj, unsigned* __restrict__ bmT){
  int gid = blockIdx.x*256 + threadIdx.x;
  int lane = threadIdx.x & 63;
  unsigned long long m = __ballot(adj[gid] > 0);
  int w = gid >> 5, i = w >> 7, jw = w & 127;
  if (lane == 0)       bmT[(size_t)jw*NN + i] = (unsigned)m;
  else if (lane == 32) bmT[(size_t)jw*NN + i] = (unsigned)(m >> 32);
}

// ---------------- WbT[h][o][k] = bf16(W[h][k][o]) ----------------
__global__ __launch_bounds__(256) void cast_W_k(const float* __restrict__ W, unsigned short* __restrict__ WbT){
  __shared__ float T[64][65];
  const int h = blockIdx.y, k0 = blockIdx.x*64, t = threadIdx.x;
  for (int idx = t; idx < 1024; idx += 256){
    int k = idx >> 4, c4 = idx & 15;
    *(float4*)&T[k][c4*4] = *(const float4*)&W[((size_t)h*F_IN + k0 + k)*HID + c4*4];
  }
  __syncthreads();
  for (int idx = t; idx < 512; idx += 256){
    int o = idx >> 3, ch = idx & 7;
    s16x8 v;
    #pragma unroll
    for (int e = 0; e < 8; ++e) v[e] = (short)f2bf(T[ch*8 + e][o]);
    *(s16x8*)&WbT[((size_t)h*HID + o)*F_IN + k0 + ch*8] = v;
  }
}

// ---------------- WoT[c][k] = bf16(W_out[k][c]), rows 40..47 zero ----------------
__global__ __launch_bounds__(256) void cast_Wo_k(const float* __restrict__ Wout, unsigned short* __restrict__ WoT){
  int idx = blockIdx.x*256 + threadIdx.x;   // 48*512
  int cc = idx >> 9, k = idx & 511;
  WoT[idx] = (cc < NCLS) ? f2bf(Wout[(size_t)k*NCLS + cc]) : (unsigned short)0;
}

// ---------------- gemm1: WhT[h][o][n] bf16 = (x@W)^T ; srcv/dstv/bdv fused epilogue ----------------
__global__ __launch_bounds__(256) void gemm1_k(const float* __restrict__ x,
    const unsigned short* __restrict__ WbT, unsigned short* __restrict__ WhT,
    const float* __restrict__ a_src, const float* __restrict__ a_dst,
    float* __restrict__ srcv, float* __restrict__ dstv, float2* __restrict__ bdv){
  __shared__ unsigned short xS[64*64];
  __shared__ unsigned short wS[64*64];
  const int t = threadIdx.x, l = t & 63, wv = t >> 6, g = l >> 4, c = l & 15;
  const int h = blockIdx.y, n0 = blockIdx.x * 64;
  f32x4 acc[4] = {};
  for (int k0 = 0; k0 < F_IN; k0 += 64){
    __syncthreads();
    #pragma unroll
    for (int p = 0; p < 4; ++p){
      int idx = t + p*256, row = idx >> 4, c4 = idx & 15;
      float4 v = *(const float4*)&x[(size_t)(n0+row)*F_IN + k0 + c4*4];
      *(uint2*)&xS[SWZ(row, c4*4)] = make_uint2(cvtpk(v.x, v.y), cvtpk(v.z, v.w));
    }
    #pragma unroll
    for (int p = 0; p < 2; ++p){
      int idx = t + p*256, o = idx >> 3, ch = idx & 7;
      *(s16x8*)&wS[SWZ(o, ch*8)] = *(const s16x8*)&WbT[(size_t)(h*HID + o)*F_IN + k0 + ch*8];
    }
    __syncthreads();
    #pragma unroll
    for (int ks = 0; ks < 2; ++ks){
      s16x8 av = *(const s16x8*)&xS[SWZ(wv*16 + c, ks*32 + g*8)];
      #pragma unroll
      for (int ct = 0; ct < 4; ++ct){
        s16x8 bv = *(const s16x8*)&wS[SWZ(ct*16 + c, ks*32 + g*8)];
        acc[ct] = __builtin_amdgcn_mfma_f32_16x16x32_bf16(av, bv, acc[ct], 0, 0, 0);
      }
    }
  }
  float asv[4], adv[4];
  #pragma unroll
  for (int ct = 0; ct < 4; ++ct){ asv[ct] = a_src[h*HID + ct*16 + c]; adv[ct] = a_dst[h*HID + ct*16 + c]; }
  #pragma unroll
  for (int r = 0; r < 4; ++r){
    float ps = acc[0][r]*asv[0] + acc[1][r]*asv[1] + acc[2][r]*asv[2] + acc[3][r]*asv[3];
    float pd = acc[0][r]*adv[0] + acc[1][r]*adv[1] + acc[2][r]*adv[2] + acc[3][r]*adv[3];
    #pragma unroll
    for (int off = 1; off < 16; off <<= 1){ ps += __shfl_xor(ps, off); pd += __shfl_xor(pd, off); }
    if (c == 0){
      int n = n0 + wv*16 + g*4 + r;
      srcv[h*NN + n] = ps; dstv[h*NN + n] = pd;
      bdv[h*NN + n] = make_float2(exp2f(pd*LOG2E), exp2f(0.2f*pd*LOG2E));
    }
  }
  __syncthreads();
  #pragma unroll
  for (int ct = 0; ct < 4; ++ct)
    *(uint2*)&xS[SWZ(ct*16 + c, wv*16 + g*4)] = make_uint2(cvtpk(acc[ct][0], acc[ct][1]), cvtpk(acc[ct][2], acc[ct][3]));
  __syncthreads();
  #pragma unroll
  for (int p = 0; p < 2; ++p){
    int idx = t + p*256, o = idx >> 3, ch = idx & 7;
    *(s16x8*)&WhT[(size_t)(h*HID + o)*NN + n0 + ch*8] = *(const s16x8*)&xS[SWZ(o, ch*8)];
  }
}

// ---------------- per-4096-segment max reduce ----------------
__global__ __launch_bounds__(256) void maxred_k(const float* __restrict__ in, float* __restrict__ out){
  __shared__ float red[4];
  const float* p = in + (size_t)blockIdx.x*NN;
  float m = -3.0e38f;
  for (int i = threadIdx.x; i < NN; i += 256) m = fmaxf(m, p[i]);
  #pragma unroll
  for (int off = 32; off; off >>= 1) m = fmaxf(m, __shfl_xor(m, off));
  if ((threadIdx.x & 63) == 0) red[threadIdx.x >> 6] = m;
  __syncthreads();
  if (threadIdx.x == 0) out[blockIdx.x] = fmaxf(fmaxf(red[0], red[1]), fmaxf(red[2], red[3]));
}

// ---------------- MFMA masked-softmax aggregate v5: 64-row shared-tile, no merge ----------------
// Block: 64 rows; 4 waves each own 16 rows (wave wv -> rows i0+wv*16..+16), ALL consume the
// same j-tile from a shared double-buffered vS (18 KB LDS).
// Per iteration: loadRegs(next) -> computeBuf(cur) -> writeLDS(cur^1) -> one barrier.
// p_ij = bit * med3(A_i*B_j, C_i*D_j, 1); (B,D) from bdv. Row sums via ones-MFMA.
// NOTE: no min-waves launch_bounds arg — r14's (256,8) forced VGPR=32 + scratch spills (74 MB writes).
// MODE 0 (L1): blockIdx.y = h*4+ck; bf16 partials [ck][row][512], fp32 den[(ck*8+h)*NN+row].
// MODE 1 (L2): blockIdx.y = ck (16 chunks); fp32 partials [ck][row][64], den in col 48.
template<int NCT, int NJT, int MODE>
__global__ __launch_bounds__(256) void agg_mfma_k(
    const unsigned* __restrict__ bmT, const unsigned short* __restrict__ VT,
    const float* __restrict__ srcv, const float2* __restrict__ bdv,
    const float* __restrict__ maxp, void* __restrict__ partOut, float* __restrict__ denOut)
{
  __shared__ unsigned short vS[2][NCT*16*64];
  __shared__ float2 dS[2][64];
  __shared__ unsigned bitS[2][2][64];
  const int t = threadIdx.x, l = t & 63, wv = t >> 6, g = l >> 4, c = l & 15;
  const int h  = (MODE == 0) ? (blockIdx.y >> 2) : 0;
  const int ck = (MODE == 0) ? (blockIdx.y & 3)  : blockIdx.y;
  const int jt0 = ck * NJT;
  const int i0 = blockIdx.x * 64;
  const int lr = wv*16 + c;                 // local row (0..63)
  const float sr = srcv[h*NN + i0 + lr];
  const float mx = maxp[MODE == 0 ? h : 0];
  const float tm = sr + mx;
  const float mi2 = fmaxf(tm, 0.2f*tm) * LOG2E;
  f32x2 ac2;
  ac2[0] = exp2f(fmaf(sr, LOG2E, -mi2));        // A_i
  ac2[1] = exp2f(fmaf(0.2f*sr, LOG2E, -mi2));   // C_i
  const unsigned short* vb = VT + (MODE == 0 ? (size_t)h*HID*NN : (size_t)0);
  const float2* bp = bdv + (MODE == 0 ? (size_t)h*NN : (size_t)0);

  f32x4 acc[NCT] = {};
  f32x4 accs = {};
  s16x8 ones;
  #pragma unroll
  for (int e = 0; e < 8; ++e) ones[e] = (short)0x3F80;

  s16x8 vreg[2]; float2 dreg = make_float2(0.f, 0.f); unsigned breg = 0;
  auto loadRegs = [&](int jt){
    #pragma unroll
    for (int p = 0; p < 2; ++p){
      int u = t + p*256;
      if (u < NCT*128){
        int o = u >> 3, chk = u & 7;
        vreg[p] = *(const s16x8*)&vb[(size_t)o*NN + jt*64 + chk*8];
      }
    }
    if (t < 64) { f32x2 bd = *(const f32x2*)&bp[jt*64 + t]; dreg = make_float2(bd[0], bd[1]); }
    else if (t < 192){ int u = t - 64; breg = bmT[(size_t)(jt*2 + (u>>6))*NN + i0 + (u & 63)]; }
  };
  auto writeLDS = [&](int b){
    #pragma unroll
    for (int p = 0; p < 2; ++p){
      int u = t + p*256;
      if (u < NCT*128){
        int o = u >> 3, chk = u & 7;
        *(s16x8*)&vS[b][SWZ(o, chk*8)] = vreg[p];
      }
    }
    if (t < 64) dS[b][t] = dreg;
    else if (t < 192){ int u = t - 64; bitS[b][u>>6][u&63] = breg; }
  };
  auto computeBuf = [&](int b){
    #pragma unroll
    for (int ks = 0; ks < 2; ++ks){
      unsigned wb = (bitS[b][ks][lr] >> (g*8)) & 0xffu;
      const f32x2* dr = (const f32x2*)&dS[b][ks*32 + g*8];
      float q[8];
      #pragma unroll
      for (int e = 0; e < 8; ++e){
        f32x2 pr = pkmul(ac2, dr[e]);
        float m3 = __builtin_amdgcn_fmed3f(pr[0], pr[1], 1.0f);
        q[e] = (wb & (1u << e)) ? m3 : 0.f;
      }
      s16x8 afr;
      ((unsigned*)&afr)[0] = cvtpk(q[0], q[1]);
      ((unsigned*)&afr)[1] = cvtpk(q[2], q[3]);
      ((unsigned*)&afr)[2] = cvtpk(q[4], q[5]);
      ((unsigned*)&afr)[3] = cvtpk(q[6], q[7]);
      #pragma unroll
      for (int ct = 0; ct < NCT; ++ct){
        s16x8 bv = *(const s16x8*)&vS[b][SWZ(ct*16 + c, ks*32 + g*8)];
        acc[ct] = __builtin_amdgcn_mfma_f32_16x16x32_bf16(afr, bv, acc[ct], 0, 0, 0);
      }
      accs = __builtin_amdgcn_mfma_f32_16x16x32_bf16(afr, ones, accs, 0, 0, 0);
    }
  };

  // prologue
  loadRegs(jt0);
  writeLDS(0);
  __syncthreads();
  int cur = 0;
  for (int jj = 0; jj < NJT; ++jj){
    const bool more = (jj + 1 < NJT);
    if (more) loadRegs(jt0 + jj + 1);   // issue next-tile loads early
    computeBuf(cur);
    if (more) writeLDS(cur ^ 1);        // write-late into other buffer
    __syncthreads();                    // single barrier per iteration
    cur ^= 1;
  }

  // epilogue: wave wv owns complete rows i0 + wv*16 + g*4 + r (no merge needed)
  if (MODE == 0){
    unsigned short* ob = (unsigned short*)partOut + (size_t)ck * NN * (NHEAD*HID);
    #pragma unroll
    for (int r = 0; r < 4; ++r){
      int row = i0 + wv*16 + g*4 + r;
      #pragma unroll
      for (int ct = 0; ct < NCT; ++ct)
        ob[(size_t)row*(NHEAD*HID) + h*HID + ct*16 + c] = f2bf(acc[ct][r]);
      if (c == 0) denOut[(size_t)(ck*NHEAD + h)*NN + row] = accs[r];
    }
  } else {
    float* ob = (float*)partOut + (size_t)ck * NN * 64;
    #pragma unroll
    for (int r = 0; r < 4; ++r){
      int row = i0 + wv*16 + g*4 + r;
      #pragma unroll
      for (int ct = 0; ct < NCT; ++ct)
        ob[(size_t)row*64 + ct*16 + c] = acc[ct][r];
      if (c == 0) ob[(size_t)row*64 + 48] = accs[r];
    }
  }
}

// ---------------- layer-1 merge: 4 bf16 chunks -> normalize -> elu -> bf16 hbuf ----------------
__global__ __launch_bounds__(256) void merge1_k(const unsigned short* __restrict__ part,
                                                const float* __restrict__ den,
                                                unsigned short* __restrict__ hb){
  int idx = blockIdx.x*256 + threadIdx.x;   // NN*128 threads
  int row = idx >> 7, q = idx & 127;
  int h = q >> 4;
  float v[4] = {0.f, 0.f, 0.f, 0.f};
  float dn = 0.f;
  #pragma unroll
  for (int ck = 0; ck < 4; ++ck){
    const unsigned short* pb = part + ((size_t)ck*NN + row)*(NHEAD*HID) + q*4;
    ushort4 u = *(const ushort4*)pb;
    v[0] += bf2f(u.x); v[1] += bf2f(u.y); v[2] += bf2f(u.z); v[3] += bf2f(u.w);
    dn += den[(size_t)(ck*NHEAD + h)*NN + row];
  }
  float inv = 1.f / fmaxf(dn, 1e-30f);
  #pragma unroll
  for (int e = 0; e < 4; ++e){
    float x = v[e]*inv;
    v[e] = x > 0.f ? x : __expf(x) - 1.f;
  }
  *(uint2*)&hb[(size_t)row*(NHEAD*HID) + q*4] = make_uint2(cvtpk(v[0], v[1]), cvtpk(v[2], v[3]));
}

// ---------------- gemm2: WhT2[c][n] bf16 = (h_bf16 @ W_out)^T ; s2/d2/bd2 fused ----------------
__global__ __launch_bounds__(256) void gemm2_k(const unsigned short* __restrict__ hb,
    const unsigned short* __restrict__ WoT, const float* __restrict__ aos, const float* __restrict__ aod,
    unsigned short* __restrict__ WhT2, float* __restrict__ s2, float* __restrict__ d2,
    float2* __restrict__ bd2){
  __shared__ unsigned short aS[64*64];
  __shared__ unsigned short bS[48*64];
  const int t = threadIdx.x, l = t & 63, wv = t >> 6, g = l >> 4, c = l & 15;
  const int n0 = blockIdx.x * 64;
  f32x4 acc[3] = {};
  for (int k0 = 0; k0 < NHEAD*HID; k0 += 64){
    __syncthreads();
    #pragma unroll
    for (int p = 0; p < 2; ++p){
      int u = t + p*256, o = u >> 3, ch = u & 7;
      *(s16x8*)&aS[SWZ(o, ch*8)] = *(const s16x8*)&hb[(size_t)(n0+o)*(NHEAD*HID) + k0 + ch*8];
    }
    for (int u = t; u < 384; u += 256){
      int o = u >> 3, ch = u & 7;
      *(s16x8*)&bS[SWZ(o, ch*8)] = *(const s16x8*)&WoT[(size_t)o*(NHEAD*HID) + k0 + ch*8];
    }
    __syncthreads();
    #pragma unroll
    for (int ks = 0; ks < 2; ++ks){
      s16x8 av = *(const s16x8*)&aS[SWZ(wv*16 + c, ks*32 + g*8)];
      #pragma unroll
      for (int ct = 0; ct < 3; ++ct){
        s16x8 bv = *(const s16x8*)&bS[SWZ(ct*16 + c, ks*32 + g*8)];
        acc[ct] = __builtin_amdgcn_mfma_f32_16x16x32_bf16(av, bv, acc[ct], 0, 0, 0);
      }
    }
  }
  float asv[3], adv[3];
  #pragma unroll
  for (int ct = 0; ct < 3; ++ct){
    int col = ct*16 + c;
    asv[ct] = (col < NCLS) ? aos[col] : 0.f;
    adv[ct] = (col < NCLS) ? aod[col] : 0.f;
  }
  #pragma unroll
  for (int r = 0; r < 4; ++r){
    float ps = acc[0][r]*asv[0] + acc[1][r]*asv[1] + acc[2][r]*asv[2];
    float pd = acc[0][r]*adv[0] + acc[1][r]*adv[1] + acc[2][r]*adv[2];
    #pragma unroll
    for (int off = 1; off < 16; off <<= 1){ ps += __shfl_xor(ps, off); pd += __shfl_xor(pd, off); }
    if (c == 0){
      int n = n0 + wv*16 + g*4 + r;
      s2[n] = ps; d2[n] = pd;
      bd2[n] = make_float2(exp2f(pd*LOG2E), exp2f(0.2f*pd*LOG2E));
    }
  }
  __syncthreads();
  #pragma unroll
  for (int ct = 0; ct < 3; ++ct)
    *(uint2*)&bS[SWZ(ct*16 + c, wv*16 + g*4)] = make_uint2(cvtpk(acc[ct][0], acc[ct][1]), cvtpk(acc[ct][2], acc[ct][3]));
  __syncthreads();
  for (int u = t; u < 384; u += 256){
    int o = u >> 3, ch = u & 7;
    *(s16x8*)&WhT2[(size_t)o*NN + n0 + ch*8] = *(const s16x8*)&bS[SWZ(o, ch*8)];
  }
}

// ---------------- merge 16 chunks + elu + row log_softmax ----------------
__global__ __launch_bounds__(256) void final_k(const float* __restrict__ part, float* __restrict__ out){
  const int wid = (blockIdx.x*256 + threadIdx.x) >> 6;
  const int c = threadIdx.x & 63;
  float acc = 0.f, rs = 0.f;
  #pragma unroll
  for (int ch = 0; ch < 16; ++ch){
    const float* pb = part + ((size_t)ch*NN + wid)*64;
    if (c < 48) acc += pb[c];
    rs += pb[48];
  }
  float v = acc / fmaxf(rs, 1e-30f);
  float e = v > 0.f ? v : __expf(v) - 1.f;
  float ev = (c < NCLS) ? e : -3.0e38f;
  float m = ev;
  #pragma unroll
  for (int off = 32; off; off >>= 1) m = fmaxf(m, __shfl_xor(m, off));
  float ex = (c < NCLS) ? __expf(e - m) : 0.f;
  float s = ex;
  #pragma unroll
  for (int off = 32; off; off >>= 1) s += __shfl_xor(s, off);
  if (c < NCLS) out[(size_t)wid*NCLS + c] = e - m - __logf(s);
}

extern "C" void kernel_launch(void* const* d_in, const int* in_sizes, int n_in,
                              void* d_out, int out_size, void* d_ws, size_t ws_size,
                              hipStream_t stream){
  (void)in_sizes; (void)n_in; (void)out_size; (void)ws_size;
  const float* x     = (const float*)d_in[0];
  const int*   adj   = (const int*)  d_in[1];
  const float* W     = (const float*)d_in[2];
  const float* a_src = (const float*)d_in[3];
  const float* a_dst = (const float*)d_in[4];
  const float* W_out = (const float*)d_in[5];
  const float* aos   = (const float*)d_in[6];
  const float* aod   = (const float*)d_in[7];
  float* out = (float*)d_out;

  char* p = (char*)d_ws;
  unsigned* bmT        = (unsigned*)p;       p += (size_t)NN*128*4;            // 2 MB
  unsigned short* WbT  = (unsigned short*)p; p += (size_t)NHEAD*HID*F_IN*2;    // 1 MB
  unsigned short* WhT  = (unsigned short*)p; p += (size_t)NHEAD*HID*NN*2;      // 4 MB
  unsigned short* hbuf = (unsigned short*)p; p += (size_t)NN*NHEAD*HID*2;      // 4 MB
  unsigned short* WoT  = (unsigned short*)p; p += (size_t)48*NHEAD*HID*2;      // 48 KB
  unsigned short* WhT2 = (unsigned short*)p; p += (size_t)48*NN*2;             // 384 KB
  float* srcv = (float*)p; p += (size_t)NHEAD*NN*4;
  float* dstv = (float*)p; p += (size_t)NHEAD*NN*4;
  float* maxd = (float*)p; p += 256;
  float* s2   = (float*)p; p += (size_t)NN*4;
  float* d2   = (float*)p; p += (size_t)NN*4;
  float* m2   = (float*)p; p += 256;
  float2* bdv1 = (float2*)p; p += (size_t)NHEAD*NN*8;                          // 256 KB
  float2* bdv2 = (float2*)p; p += (size_t)NN*8;                                // 32 KB
  float* den1 = (float*)p; p += (size_t)4*NHEAD*NN*4;                          // 512 KB
  char* partU = p; p += (size_t)16*NN*64*4;                                    // 16 MB (L1 bf16 4-chunk / L2 fp32 16-chunk)

  pack_adj_k<<<(NN*NN)/256, 256, 0, stream>>>(adj, bmT);
  cast_W_k<<<dim3(F_IN/64, NHEAD), 256, 0, stream>>>(W, WbT);
  cast_Wo_k<<<96, 256, 0, stream>>>(W_out, WoT);
  gemm1_k<<<dim3(NN/64, NHEAD), 256, 0, stream>>>(x, WbT, WhT, a_src, a_dst, srcv, dstv, bdv1);
  maxred_k<<<NHEAD, 256, 0, stream>>>(dstv, maxd);
  agg_mfma_k<4, 16, 0><<<dim3(NN/64, NHEAD*4), 256, 0, stream>>>(bmT, WhT, srcv, bdv1, maxd, partU, den1);
  merge1_k<<<(NN*128)/256, 256, 0, stream>>>((const unsigned short*)partU, den1, hbuf);
  gemm2_k<<<NN/64, 256, 0, stream>>>(hbuf, WoT, aos, aod, WhT2, s2, d2, bdv2);
  maxred_k<<<1, 256, 0, stream>>>(d2, m2);
  agg_mfma_k<3, 4, 1><<<dim3(NN/64, 16), 256, 0, stream>>>(bmT, WhT2, s2, bdv2, m2, partU, nullptr);
  final_k<<<NN/4, 256, 0, stream>>>((const float*)partU, out);
}

// Round 16
// 159.085 us; speedup vs baseline: 1.1176x; 1.0085x over previous
//
#include <hip/hip_runtime.h>

#define NN 4096
#define F_IN 1024
#define NHEAD 8
#define HID 64
#define NCLS 40
#define LOG2E 1.44269504f

typedef float f32x4 __attribute__((ext_vector_type(4)));
typedef float f32x2 __attribute__((ext_vector_type(2)));
typedef float f32x16 __attribute__((ext_vector_type(16)));
typedef short s16x8 __attribute__((ext_vector_type(8)));

// XOR-swizzled halfword index within a [R][64]-hw (128B-row) LDS tile.
#define SWZ(r,c) (((r)*64) + ((c) ^ (((r)&7)<<3)))

__device__ __forceinline__ unsigned short f2bf(float f){  // RNE float->bf16
  unsigned u = __float_as_uint(f);
  return (unsigned short)((u + 0x7fffu + ((u >> 16) & 1u)) >> 16);
}
__device__ __forceinline__ float bf2f(unsigned short u){
  return __uint_as_float((unsigned)u << 16);
}
__device__ __forceinline__ unsigned cvtpk(float lo, float hi){  // packed bf16 pair
  unsigned r; asm("v_cvt_pk_bf16_f32 %0, %1, %2" : "=v"(r) : "v"(lo), "v"(hi)); return r;
}
__device__ __forceinline__ f32x2 pkmul(f32x2 a, f32x2 b){  // packed fp32 dual mul
  f32x2 r; asm("v_pk_mul_f32 %0, %1, %2" : "=v"(r) : "v"(a), "v"(b)); return r;
}

// ---------------- pack adjacency -> word-transposed bitmask ----------------
__global__ __launch_bounds__(256) void pack_adj_k(const int* __restrict__ adj, unsigned* __restrict__ bmT){
  int gid = blockIdx.x*256 + threadIdx.x;
  int lane = threadIdx.x & 63;
  unsigned long long m = __ballot(adj[gid] > 0);
  int w = gid >> 5, i = w >> 7, jw = w & 127;
  if (lane == 0)       bmT[(size_t)jw*NN + i] = (unsigned)m;
  else if (lane == 32) bmT[(size_t)jw*NN + i] = (unsigned)(m >> 32);
}

// ---------------- WbT[h][o][k] = bf16(W[h][k][o]) ----------------
__global__ __launch_bounds__(256) void cast_W_k(const float* __restrict__ W, unsigned short* __restrict__ WbT){
  __shared__ float T[64][65];
  const int h = blockIdx.y, k0 = blockIdx.x*64, t = threadIdx.x;
  for (int idx = t; idx < 1024; idx += 256){
    int k = idx >> 4, c4 = idx & 15;
    *(float4*)&T[k][c4*4] = *(const float4*)&W[((size_t)h*F_IN + k0 + k)*HID + c4*4];
  }
  __syncthreads();
  for (int idx = t; idx < 512; idx += 256){
    int o = idx >> 3, ch = idx & 7;
    s16x8 v;
    #pragma unroll
    for (int e = 0; e < 8; ++e) v[e] = (short)f2bf(T[ch*8 + e][o]);
    *(s16x8*)&WbT[((size_t)h*HID + o)*F_IN + k0 + ch*8] = v;
  }
}

// ---------------- WoT[c][k] = bf16(W_out[k][c]), rows 40..47 zero ----------------
__global__ __launch_bounds__(256) void cast_Wo_k(const float* __restrict__ Wout, unsigned short* __restrict__ WoT){
  int idx = blockIdx.x*256 + threadIdx.x;   // 48*512
  int cc = idx >> 9, k = idx & 511;
  WoT[idx] = (cc < NCLS) ? f2bf(Wout[(size_t)k*NCLS + cc]) : (unsigned short)0;
}

// ---------------- gemm1: WhT[h][o][n] bf16 = (x@W)^T ; srcv/dstv/bdv fused epilogue ----------------
__global__ __launch_bounds__(256) void gemm1_k(const float* __restrict__ x,
    const unsigned short* __restrict__ WbT, unsigned short* __restrict__ WhT,
    const float* __restrict__ a_src, const float* __restrict__ a_dst,
    float* __restrict__ srcv, float* __restrict__ dstv, float2* __restrict__ bdv){
  __shared__ unsigned short xS[64*64];
  __shared__ unsigned short wS[64*64];
  const int t = threadIdx.x, l = t & 63, wv = t >> 6, g = l >> 4, c = l & 15;
  const int h = blockIdx.y, n0 = blockIdx.x * 64;
  f32x4 acc[4] = {};
  for (int k0 = 0; k0 < F_IN; k0 += 64){
    __syncthreads();
    #pragma unroll
    for (int p = 0; p < 4; ++p){
      int idx = t + p*256, row = idx >> 4, c4 = idx & 15;
      float4 v = *(const float4*)&x[(size_t)(n0+row)*F_IN + k0 + c4*4];
      *(uint2*)&xS[SWZ(row, c4*4)] = make_uint2(cvtpk(v.x, v.y), cvtpk(v.z, v.w));
    }
    #pragma unroll
    for (int p = 0; p < 2; ++p){
      int idx = t + p*256, o = idx >> 3, ch = idx & 7;
      *(s16x8*)&wS[SWZ(o, ch*8)] = *(const s16x8*)&WbT[(size_t)(h*HID + o)*F_IN + k0 + ch*8];
    }
    __syncthreads();
    #pragma unroll
    for (int ks = 0; ks < 2; ++ks){
      s16x8 av = *(const s16x8*)&xS[SWZ(wv*16 + c, ks*32 + g*8)];
      #pragma unroll
      for (int ct = 0; ct < 4; ++ct){
        s16x8 bv = *(const s16x8*)&wS[SWZ(ct*16 + c, ks*32 + g*8)];
        acc[ct] = __builtin_amdgcn_mfma_f32_16x16x32_bf16(av, bv, acc[ct], 0, 0, 0);
      }
    }
  }
  float asv[4], adv[4];
  #pragma unroll
  for (int ct = 0; ct < 4; ++ct){ asv[ct] = a_src[h*HID + ct*16 + c]; adv[ct] = a_dst[h*HID + ct*16 + c]; }
  #pragma unroll
  for (int r = 0; r < 4; ++r){
    float ps = acc[0][r]*asv[0] + acc[1][r]*asv[1] + acc[2][r]*asv[2] + acc[3][r]*asv[3];
    float pd = acc[0][r]*adv[0] + acc[1][r]*adv[1] + acc[2][r]*adv[2] + acc[3][r]*adv[3];
    #pragma unroll
    for (int off = 1; off < 16; off <<= 1){ ps += __shfl_xor(ps, off); pd += __shfl_xor(pd, off); }
    if (c == 0){
      int n = n0 + wv*16 + g*4 + r;
      srcv[h*NN + n] = ps; dstv[h*NN + n] = pd;
      bdv[h*NN + n] = make_float2(exp2f(pd*LOG2E), exp2f(0.2f*pd*LOG2E));
    }
  }
  __syncthreads();
  #pragma unroll
  for (int ct = 0; ct < 4; ++ct)
    *(uint2*)&xS[SWZ(ct*16 + c, wv*16 + g*4)] = make_uint2(cvtpk(acc[ct][0], acc[ct][1]), cvtpk(acc[ct][2], acc[ct][3]));
  __syncthreads();
  #pragma unroll
  for (int p = 0; p < 2; ++p){
    int idx = t + p*256, o = idx >> 3, ch = idx & 7;
    *(s16x8*)&WhT[(size_t)(h*HID + o)*NN + n0 + ch*8] = *(const s16x8*)&xS[SWZ(o, ch*8)];
  }
}

// ---------------- per-4096-segment max reduce ----------------
__global__ __launch_bounds__(256) void maxred_k(const float* __restrict__ in, float* __restrict__ out){
  __shared__ float red[4];
  const float* p = in + (size_t)blockIdx.x*NN;
  float m = -3.0e38f;
  for (int i = threadIdx.x; i < NN; i += 256) m = fmaxf(m, p[i]);
  #pragma unroll
  for (int off = 32; off; off >>= 1) m = fmaxf(m, __shfl_xor(m, off));
  if ((threadIdx.x & 63) == 0) red[threadIdx.x >> 6] = m;
  __syncthreads();
  if (threadIdx.x == 0) out[blockIdx.x] = fmaxf(fmaxf(red[0], red[1]), fmaxf(red[2], red[3]));
}

// ---------------- L1 aggregate v6: 32x32x16 MFMA, 128-row blocks ----------------
// 4 waves x 32-row fragments, 2 col-fragments (HID=64), K=16 slices; shared dbuf V tile (8KB).
// Ping-pong: loadRegs(next) -> computeBuf(cur) -> writeLDS(cur^1) -> one barrier.
// A layout: row=l&31, k=(l>>5)*8+e. C/D: col=l&31, row=(r&3)+8*(r>>2)+4*(l>>5).
// p_ij = bit * med3(A_i*B_j, C_i*D_j, 1); row sums via per-lane adds + shfl_xor(32).
// blockIdx.y = h*8+ck (8 chunks, NJT=8). bf16 partials [ck][row][512]; fp32 den[(ck*8+h)*NN+row].
template<int NJT>
__global__ __launch_bounds__(256) void agg32_k(
    const unsigned* __restrict__ bmT, const unsigned short* __restrict__ VT,
    const float* __restrict__ srcv, const float2* __restrict__ bdv,
    const float* __restrict__ maxp, unsigned short* __restrict__ partOut, float* __restrict__ denOut)
{
  __shared__ unsigned short vS[2][64*64];
  __shared__ float2 dS[2][64];
  __shared__ unsigned bitS[2][2][128];
  const int t = threadIdx.x, l = t & 63, wv = t >> 6, hk = l >> 5, lr31 = l & 31;
  const int h  = blockIdx.y >> 3;
  const int ck = blockIdx.y & 7;
  const int jt0 = ck * NJT;
  const int i0 = blockIdx.x * 128;
  const int lr = wv*32 + lr31;              // local row (0..127)
  const float sr = srcv[h*NN + i0 + lr];
  const float mx = maxp[h];
  const float tm = sr + mx;
  const float mi2 = fmaxf(tm, 0.2f*tm) * LOG2E;
  f32x2 ac2;
  ac2[0] = exp2f(fmaf(sr, LOG2E, -mi2));        // A_i
  ac2[1] = exp2f(fmaf(0.2f*sr, LOG2E, -mi2));   // C_i
  const unsigned short* vb = VT + (size_t)h*HID*NN;
  const float2* bp = bdv + (size_t)h*NN;

  f32x16 acc[2] = {};
  float rs = 0.f;

  s16x8 vreg[2]; float2 dreg = make_float2(0.f, 0.f); unsigned breg = 0;
  auto loadRegs = [&](int jt){
    #pragma unroll
    for (int p = 0; p < 2; ++p){
      int u = t + p*256, o = u >> 3, chk = u & 7;
      vreg[p] = *(const s16x8*)&vb[(size_t)o*NN + jt*64 + chk*8];
    }
    if (t < 64){ f32x2 bd = *(const f32x2*)&bp[jt*64 + t]; dreg = make_float2(bd[0], bd[1]); }
    breg = bmT[(size_t)(jt*2 + (t>>7))*NN + i0 + (t & 127)];
  };
  auto writeLDS = [&](int b){
    #pragma unroll
    for (int p = 0; p < 2; ++p){
      int u = t + p*256, o = u >> 3, chk = u & 7;
      *(s16x8*)&vS[b][SWZ(o, chk*8)] = vreg[p];
    }
    if (t < 64) dS[b][t] = dreg;
    bitS[b][t>>7][t & 127] = breg;
  };
  auto computeBuf = [&](int b){
    #pragma unroll
    for (int ksl = 0; ksl < 4; ++ksl){
      const int b0 = ksl*16 + hk*8;                 // k offset within 64-j tile
      unsigned wb = (bitS[b][b0 >> 5][lr] >> (b0 & 31)) & 0xffu;
      const f32x2* dr = (const f32x2*)&dS[b][b0];
      float q[8];
      #pragma unroll
      for (int e = 0; e < 8; ++e){
        f32x2 pr = pkmul(ac2, dr[e]);
        float m3 = __builtin_amdgcn_fmed3f(pr[0], pr[1], 1.0f);
        q[e] = (wb & (1u << e)) ? m3 : 0.f;
      }
      rs += ((q[0]+q[1])+(q[2]+q[3])) + ((q[4]+q[5])+(q[6]+q[7]));
      s16x8 afr;
      ((unsigned*)&afr)[0] = cvtpk(q[0], q[1]);
      ((unsigned*)&afr)[1] = cvtpk(q[2], q[3]);
      ((unsigned*)&afr)[2] = cvtpk(q[4], q[5]);
      ((unsigned*)&afr)[3] = cvtpk(q[6], q[7]);
      #pragma unroll
      for (int cf = 0; cf < 2; ++cf){
        s16x8 bv = *(const s16x8*)&vS[b][SWZ(cf*32 + lr31, b0)];
        acc[cf] = __builtin_amdgcn_mfma_f32_32x32x16_bf16(afr, bv, acc[cf], 0, 0, 0);
      }
    }
  };

  // prologue
  loadRegs(jt0);
  writeLDS(0);
  __syncthreads();
  int cur = 0;
  for (int jj = 0; jj < NJT; ++jj){
    const bool more = (jj + 1 < NJT);
    if (more) loadRegs(jt0 + jj + 1);
    computeBuf(cur);
    if (more) writeLDS(cur ^ 1);
    __syncthreads();
    cur ^= 1;
  }

  // row sums: lane pair (l, l^32) covers all k for row lr31
  rs += __shfl_xor(rs, 32);
  if (l < 32 && wv >= 0){
    denOut[(size_t)(ck*NHEAD + h)*NN + i0 + wv*32 + l] = rs;
  }
  // bf16 partials: C/D row = (r&3)+8*(r>>2)+4*hk, col = cf*32 + lr31
  unsigned short* ob = partOut + (size_t)ck * NN * (NHEAD*HID);
  #pragma unroll
  for (int cf = 0; cf < 2; ++cf){
    #pragma unroll
    for (int r = 0; r < 16; ++r){
      int row = i0 + wv*32 + (r & 3) + 8*(r >> 2) + 4*hk;
      ob[(size_t)row*(NHEAD*HID) + h*HID + cf*32 + lr31] = f2bf(acc[cf][r]);
    }
  }
}

// ---------------- L2 MFMA aggregate (r15-verbatim, MODE 1 path) ----------------
// Block: 64 rows; 4 waves each own 16 rows; shared dbuf V tile. fp32 partials, den in col 48.
template<int NCT, int NJT>
__global__ __launch_bounds__(256) void agg_mfma_k(
    const unsigned* __restrict__ bmT, const unsigned short* __restrict__ VT,
    const float* __restrict__ srcv, const float2* __restrict__ bdv,
    const float* __restrict__ maxp, void* __restrict__ partOut)
{
  __shared__ unsigned short vS[2][NCT*16*64];
  __shared__ float2 dS[2][64];
  __shared__ unsigned bitS[2][2][64];
  const int t = threadIdx.x, l = t & 63, wv = t >> 6, g = l >> 4, c = l & 15;
  const int ck = blockIdx.y;
  const int jt0 = ck * NJT;
  const int i0 = blockIdx.x * 64;
  const int lr = wv*16 + c;
  const float sr = srcv[i0 + lr];
  const float mx = maxp[0];
  const float tm = sr + mx;
  const float mi2 = fmaxf(tm, 0.2f*tm) * LOG2E;
  f32x2 ac2;
  ac2[0] = exp2f(fmaf(sr, LOG2E, -mi2));
  ac2[1] = exp2f(fmaf(0.2f*sr, LOG2E, -mi2));
  const unsigned short* vb = VT;
  const float2* bp = bdv;

  f32x4 acc[NCT] = {};
  f32x4 accs = {};
  s16x8 ones;
  #pragma unroll
  for (int e = 0; e < 8; ++e) ones[e] = (short)0x3F80;

  s16x8 vreg[2]; float2 dreg = make_float2(0.f, 0.f); unsigned breg = 0;
  auto loadRegs = [&](int jt){
    #pragma unroll
    for (int p = 0; p < 2; ++p){
      int u = t + p*256;
      if (u < NCT*128){
        int o = u >> 3, chk = u & 7;
        vreg[p] = *(const s16x8*)&vb[(size_t)o*NN + jt*64 + chk*8];
      }
    }
    if (t < 64) { f32x2 bd = *(const f32x2*)&bp[jt*64 + t]; dreg = make_float2(bd[0], bd[1]); }
    else if (t < 192){ int u = t - 64; breg = bmT[(size_t)(jt*2 + (u>>6))*NN + i0 + (u & 63)]; }
  };
  auto writeLDS = [&](int b){
    #pragma unroll
    for (int p = 0; p < 2; ++p){
      int u = t + p*256;
      if (u < NCT*128){
        int o = u >> 3, chk = u & 7;
        *(s16x8*)&vS[b][SWZ(o, chk*8)] = vreg[p];
      }
    }
    if (t < 64) dS[b][t] = dreg;
    else if (t < 192){ int u = t - 64; bitS[b][u>>6][u&63] = breg; }
  };
  auto computeBuf = [&](int b){
    #pragma unroll
    for (int ks = 0; ks < 2; ++ks){
      unsigned wb = (bitS[b][ks][lr] >> (g*8)) & 0xffu;
      const f32x2* dr = (const f32x2*)&dS[b][ks*32 + g*8];
      float q[8];
      #pragma unroll
      for (int e = 0; e < 8; ++e){
        f32x2 pr = pkmul(ac2, dr[e]);
        float m3 = __builtin_amdgcn_fmed3f(pr[0], pr[1], 1.0f);
        q[e] = (wb & (1u << e)) ? m3 : 0.f;
      }
      s16x8 afr;
      ((unsigned*)&afr)[0] = cvtpk(q[0], q[1]);
      ((unsigned*)&afr)[1] = cvtpk(q[2], q[3]);
      ((unsigned*)&afr)[2] = cvtpk(q[4], q[5]);
      ((unsigned*)&afr)[3] = cvtpk(q[6], q[7]);
      #pragma unroll
      for (int ct = 0; ct < NCT; ++ct){
        s16x8 bv = *(const s16x8*)&vS[b][SWZ(ct*16 + c, ks*32 + g*8)];
        acc[ct] = __builtin_amdgcn_mfma_f32_16x16x32_bf16(afr, bv, acc[ct], 0, 0, 0);
      }
      accs = __builtin_amdgcn_mfma_f32_16x16x32_bf16(afr, ones, accs, 0, 0, 0);
    }
  };

  loadRegs(jt0);
  writeLDS(0);
  __syncthreads();
  int cur = 0;
  for (int jj = 0; jj < NJT; ++jj){
    const bool more = (jj + 1 < NJT);
    if (more) loadRegs(jt0 + jj + 1);
    computeBuf(cur);
    if (more) writeLDS(cur ^ 1);
    __syncthreads();
    cur ^= 1;
  }

  float* ob = (float*)partOut + (size_t)ck * NN * 64;
  #pragma unroll
  for (int r = 0; r < 4; ++r){
    int row = i0 + wv*16 + g*4 + r;
    #pragma unroll
    for (int ct = 0; ct < NCT; ++ct)
      ob[(size_t)row*64 + ct*16 + c] = acc[ct][r];
    if (c == 0) ob[(size_t)row*64 + 48] = accs[r];
  }
}

// ---------------- layer-1 merge: 8 bf16 chunks -> normalize -> elu -> bf16 hbuf ----------------
__global__ __launch_bounds__(256) void merge1_k(const unsigned short* __restrict__ part,
                                                const float* __restrict__ den,
                                                unsigned short* __restrict__ hb){
  int idx = blockIdx.x*256 + threadIdx.x;   // NN*128 threads
  int row = idx >> 7, q = idx & 127;
  int h = q >> 4;
  float v[4] = {0.f, 0.f, 0.f, 0.f};
  float dn = 0.f;
  #pragma unroll
  for (int ck = 0; ck < 8; ++ck){
    const unsigned short* pb = part + ((size_t)ck*NN + row)*(NHEAD*HID) + q*4;
    ushort4 u = *(const ushort4*)pb;
    v[0] += bf2f(u.x); v[1] += bf2f(u.y); v[2] += bf2f(u.z); v[3] += bf2f(u.w);
    dn += den[(size_t)(ck*NHEAD + h)*NN + row];
  }
  float inv = 1.f / fmaxf(dn, 1e-30f);
  #pragma unroll
  for (int e = 0; e < 4; ++e){
    float x = v[e]*inv;
    v[e] = x > 0.f ? x : __expf(x) - 1.f;
  }
  *(uint2*)&hb[(size_t)row*(NHEAD*HID) + q*4] = make_uint2(cvtpk(v[0], v[1]), cvtpk(v[2], v[3]));
}

// ---------------- gemm2: WhT2[c][n] bf16 = (h_bf16 @ W_out)^T ; s2/d2/bd2 fused ----------------
__global__ __launch_bounds__(256) void gemm2_k(const unsigned short* __restrict__ hb,
    const unsigned short* __restrict__ WoT, const float* __restrict__ aos, const float* __restrict__ aod,
    unsigned short* __restrict__ WhT2, float* __restrict__ s2, float* __restrict__ d2,
    float2* __restrict__ bd2){
  __shared__ unsigned short aS[64*64];
  __shared__ unsigned short bS[48*64];
  const int t = threadIdx.x, l = t & 63, wv = t >> 6, g = l >> 4, c = l & 15;
  const int n0 = blockIdx.x * 64;
  f32x4 acc[3] = {};
  for (int k0 = 0; k0 < NHEAD*HID; k0 += 64){
    __syncthreads();
    #pragma unroll
    for (int p = 0; p < 2; ++p){
      int u = t + p*256, o = u >> 3, ch = u & 7;
      *(s16x8*)&aS[SWZ(o, ch*8)] = *(const s16x8*)&hb[(size_t)(n0+o)*(NHEAD*HID) + k0 + ch*8];
    }
    for (int u = t; u < 384; u += 256){
      int o = u >> 3, ch = u & 7;
      *(s16x8*)&bS[SWZ(o, ch*8)] = *(const s16x8*)&WoT[(size_t)o*(NHEAD*HID) + k0 + ch*8];
    }
    __syncthreads();
    #pragma unroll
    for (int ks = 0; ks < 2; ++ks){
      s16x8 av = *(const s16x8*)&aS[SWZ(wv*16 + c, ks*32 + g*8)];
      #pragma unroll
      for (int ct = 0; ct < 3; ++ct){
        s16x8 bv = *(const s16x8*)&bS[SWZ(ct*16 + c, ks*32 + g*8)];
        acc[ct] = __builtin_amdgcn_mfma_f32_16x16x32_bf16(av, bv, acc[ct], 0, 0, 0);
      }
    }
  }
  float asv[3], adv[3];
  #pragma unroll
  for (int ct = 0; ct < 3; ++ct){
    int col = ct*16 + c;
    asv[ct] = (col < NCLS) ? aos[col] : 0.f;
    adv[ct] = (col < NCLS) ? aod[col] : 0.f;
  }
  #pragma unroll
  for (int r = 0; r < 4; ++r){
    float ps = acc[0][r]*asv[0] + acc[1][r]*asv[1] + acc[2][r]*asv[2];
    float pd = acc[0][r]*adv[0] + acc[1][r]*adv[1] + acc[2][r]*adv[2];
    #pragma unroll
    for (int off = 1; off < 16; off <<= 1){ ps += __shfl_xor(ps, off); pd += __shfl_xor(pd, off); }
    if (c == 0){
      int n = n0 + wv*16 + g*4 + r;
      s2[n] = ps; d2[n] = pd;
      bd2[n] = make_float2(exp2f(pd*LOG2E), exp2f(0.2f*pd*LOG2E));
    }
  }
  __syncthreads();
  #pragma unroll
  for (int ct = 0; ct < 3; ++ct)
    *(uint2*)&bS[SWZ(ct*16 + c, wv*16 + g*4)] = make_uint2(cvtpk(acc[ct][0], acc[ct][1]), cvtpk(acc[ct][2], acc[ct][3]));
  __syncthreads();
  for (int u = t; u < 384; u += 256){
    int o = u >> 3, ch = u & 7;
    *(s16x8*)&WhT2[(size_t)o*NN + n0 + ch*8] = *(const s16x8*)&bS[SWZ(o, ch*8)];
  }
}

// ---------------- merge 16 chunks + elu + row log_softmax ----------------
__global__ __launch_bounds__(256) void final_k(const float* __restrict__ part, float* __restrict__ out){
  const int wid = (blockIdx.x*256 + threadIdx.x) >> 6;
  const int c = threadIdx.x & 63;
  float acc = 0.f, rs = 0.f;
  #pragma unroll
  for (int ch = 0; ch < 16; ++ch){
    const float* pb = part + ((size_t)ch*NN + wid)*64;
    if (c < 48) acc += pb[c];
    rs += pb[48];
  }
  float v = acc / fmaxf(rs, 1e-30f);
  float e = v > 0.f ? v : __expf(v) - 1.f;
  float ev = (c < NCLS) ? e : -3.0e38f;
  float m = ev;
  #pragma unroll
  for (int off = 32; off; off >>= 1) m = fmaxf(m, __shfl_xor(m, off));
  float ex = (c < NCLS) ? __expf(e - m) : 0.f;
  float s = ex;
  #pragma unroll
  for (int off = 32; off; off >>= 1) s += __shfl_xor(s, off);
  if (c < NCLS) out[(size_t)wid*NCLS + c] = e - m - __logf(s);
}

extern "C" void kernel_launch(void* const* d_in, const int* in_sizes, int n_in,
                              void* d_out, int out_size, void* d_ws, size_t ws_size,
                              hipStream_t stream){
  (void)in_sizes; (void)n_in; (void)out_size; (void)ws_size;
  const float* x     = (const float*)d_in[0];
  const int*   adj   = (const int*)  d_in[1];
  const float* W     = (const float*)d_in[2];
  const float* a_src = (const float*)d_in[3];
  const float* a_dst = (const float*)d_in[4];
  const float* W_out = (const float*)d_in[5];
  const float* aos   = (const float*)d_in[6];
  const float* aod   = (const float*)d_in[7];
  float* out = (float*)d_out;

  char* p = (char*)d_ws;
  unsigned* bmT        = (unsigned*)p;       p += (size_t)NN*128*4;            // 2 MB
  unsigned short* WbT  = (unsigned short*)p; p += (size_t)NHEAD*HID*F_IN*2;    // 1 MB
  unsigned short* WhT  = (unsigned short*)p; p += (size_t)NHEAD*HID*NN*2;      // 4 MB
  unsigned short* hbuf = (unsigned short*)p; p += (size_t)NN*NHEAD*HID*2;      // 4 MB
  unsigned short* WoT  = (unsigned short*)p; p += (size_t)48*NHEAD*HID*2;      // 48 KB
  unsigned short* WhT2 = (unsigned short*)p; p += (size_t)48*NN*2;             // 384 KB
  float* srcv = (float*)p; p += (size_t)NHEAD*NN*4;
  float* dstv = (float*)p; p += (size_t)NHEAD*NN*4;
  float* maxd = (float*)p; p += 256;
  float* s2   = (float*)p; p += (size_t)NN*4;
  float* d2   = (float*)p; p += (size_t)NN*4;
  float* m2   = (float*)p; p += 256;
  float2* bdv1 = (float2*)p; p += (size_t)NHEAD*NN*8;                          // 256 KB
  float2* bdv2 = (float2*)p; p += (size_t)NN*8;                                // 32 KB
  float* den1 = (float*)p; p += (size_t)8*NHEAD*NN*4;                          // 1 MB
  char* partU = p; p += (size_t)8*NN*512*2;                                    // 32 MB (L1 bf16 8-chunk; L2 fp32 16-chunk fits in 16 MB)

  pack_adj_k<<<(NN*NN)/256, 256, 0, stream>>>(adj, bmT);
  cast_W_k<<<dim3(F_IN/64, NHEAD), 256, 0, stream>>>(W, WbT);
  cast_Wo_k<<<96, 256, 0, stream>>>(W_out, WoT);
  gemm1_k<<<dim3(NN/64, NHEAD), 256, 0, stream>>>(x, WbT, WhT, a_src, a_dst, srcv, dstv, bdv1);
  maxred_k<<<NHEAD, 256, 0, stream>>>(dstv, maxd);
  agg32_k<8><<<dim3(NN/128, NHEAD*8), 256, 0, stream>>>(bmT, WhT, srcv, bdv1, maxd,
                                                        (unsigned short*)partU, den1);
  merge1_k<<<(NN*128)/256, 256, 0, stream>>>((const unsigned short*)partU, den1, hbuf);
  gemm2_k<<<NN/64, 256, 0, stream>>>(hbuf, WoT, aos, aod, WhT2, s2, d2, bdv2);
  maxred_k<<<1, 256, 0, stream>>>(d2, m2);
  agg_mfma_k<3, 4><<<dim3(NN/64, 16), 256, 0, stream>>>(bmT, WhT2, s2, bdv2, m2, partU);
  final_k<<<NN/4, 256, 0, stream>>>((const float*)partU, out);
}